// Round 5
// baseline (89.170 us; speedup 1.0000x reference)
//
#include <hip/hip_runtime.h>

// Hausdorff adv2ori via MFMA: B=8, K=8192.
// dist(n,m) = oo_n + aa_m - 2*o.a ; C = mfma(A',B') = oo_n - 2*o.a (fp16 hi/lo split)
// loss = mean_b( w_b * max_m min_n dist )
//
// K=16 slot packing (one 32x32x16_f16 MFMA per 32x32 pair tile):
//   A'(ori n): [oh.x oh.y oh.z | oh.x oh.y oh.z | ol.x ol.y ol.z | oo_h oo_l | 0 x5]
//   B'(adv m): [bh.x bh.y bh.z | bl.x bl.y bl.z | bh.x bh.y bh.z | 1    1    | 0 x5]
//   b = -2*a; dropped ol.bl terms ~1e-6; fp32 accumulate. absmax=0 in R1-R4.
//
// R4 post-mortem: hausdorff ~30us vs 6.9us matrix floor; LDS-conflict fix bought
// only ~2us -> kernel is VALU-issue/staging-structure bound (min trees + LDS
// staging instrs + per-chunk barrier drains), not LDS-pipe bound.
// R5: prep kernel materializes A' in global (tile-planar, wave reads 1KB
// contiguous); main is barrier-free, LDS-free: {1 global A-frag load, 4 MFMA,
// 4x 8-op min3 trees} per tile, 4 cols/wave (CBLK=512, 4 MFMA per A-load),
// grid 1024 = 4 blocks/CU. Same-(b,ns) blocks land on one XCD (bid%8) -> A'
// slice L2-resident. Matrix-pipe-bound target ~9-12us.

#define KPTS 8192
#define BATCH 8
#define NSPLIT 8                      // row slices (== XCD count, bid&7)
#define RBLK (KPTS / NSPLIT)          // 1024 rows per slice
#define TSLICE (RBLK / 32)            // 32 MFMA row-tiles per slice
#define CBLK 512                      // adv columns per block (4 waves x 128)
#define MCHUNK (KPTS / CBLK)          // 16
#define AHALF_B (KPTS * 16)           // halfs per batch in A' (256 KB)

typedef _Float16 half8 __attribute__((ext_vector_type(8)));
typedef float f32x16 __attribute__((ext_vector_type(16)));

// min over 16 accum values folded into running min rm: 8 min3-fusable ops.
__device__ __forceinline__ float min16acc(float rm, const f32x16 c) {
    float u0 = fminf(fminf(c[0],  c[1]),  c[2]);
    float u1 = fminf(fminf(c[3],  c[4]),  c[5]);
    float u2 = fminf(fminf(c[6],  c[7]),  c[8]);
    float u3 = fminf(fminf(c[9],  c[10]), c[11]);
    float u4 = fminf(fminf(c[12], c[13]), c[14]);
    float u5 = fminf(fminf(u0, u1), c[15]);
    float u6 = fminf(fminf(u2, u3), u4);
    return fminf(fminf(u5, u6), rm);
}

// A'-builder: point n of batch b -> tile-planar layout
//   half-offset = b*131072 + (n>>5)*512 + khalf*256 + (n&31)*8
// so a wave (lane l: r=l&31, hk=l>>5) reads one tile as 1 KB contiguous.
__global__ __launch_bounds__(256) void prep(const float* __restrict__ ori,
                                            _Float16* __restrict__ Ap) {
    const int g = blockIdx.x * 256 + threadIdx.x;   // 0..65535
    const int b = g >> 13;
    const int n = g & (KPTS - 1);

    const float* op = ori + (size_t)g * 3;
    float x = op[0], y = op[1], z = op[2];
    float oo = x * x + y * y + z * z;
    const _Float16 Z = (_Float16)0.0f;
    _Float16 hx = (_Float16)x, hy = (_Float16)y, hz = (_Float16)z;
    _Float16 lx = (_Float16)(x - (float)hx);
    _Float16 ly = (_Float16)(y - (float)hy);
    _Float16 lz = (_Float16)(z - (float)hz);
    _Float16 oh = (_Float16)oo;
    _Float16 ol = (_Float16)(oo - (float)oh);
    half8 a0 = {hx, hy, hz, hx, hy, hz, lx, ly};
    half8 a1 = {lz, oh, ol, Z, Z, Z, Z, Z};

    _Float16* base = Ap + (size_t)b * AHALF_B + ((n >> 5) << 9) + ((n & 31) << 3);
    *(half8*)base         = a0;
    *(half8*)(base + 256) = a1;
}

// Barrier-free main: block = (batch, 512-column chunk, row slice).
// Per tile: 1 contiguous 16B/lane A-frag load (L2-hot), 4 MFMA, 4 min trees.
__global__ __launch_bounds__(256) void hausdorff(const float* __restrict__ adv,
                                                 const _Float16* __restrict__ Ap,
                                                 float* __restrict__ part,
                                                 float* __restrict__ out) {
    const int bid  = blockIdx.x;          // grid = 8 * 16 * 8 = 1024
    const int b    = bid >> 7;
    const int mc   = (bid >> 3) & (MCHUNK - 1);
    const int ns   = bid & 7;
    const int tid  = threadIdx.x;
    const int lane = tid & 63;
    const int wv   = tid >> 6;
    const int r    = lane & 31;           // MFMA row/col index
    const int hk   = lane >> 5;           // K-half

    if (bid == 0 && tid == 0) out[0] = 0.0f;   // for reduceB's atomicAdd

    const _Float16 Z = (_Float16)0.0f, ONE = (_Float16)1.0f;

    // ---- B-fragments + aa for this wave's 4 column groups ----
    const float* advb = adv + (size_t)b * KPTS * 3;
    const int m0 = mc * CBLK + wv * 128 + r;
    half8 bf0, bf1, bf2, bf3;
    float aa0, aa1, aa2, aa3;
#pragma unroll
    for (int i = 0; i < 4; ++i) {
        const int m = m0 + 32 * i;
        float ax = advb[3 * m], ay = advb[3 * m + 1], az = advb[3 * m + 2];
        float aa = ax * ax + ay * ay + az * az;
        float tx = -2.f * ax, ty = -2.f * ay, tz = -2.f * az;
        _Float16 bx = (_Float16)tx, by = (_Float16)ty, bz = (_Float16)tz;
        _Float16 cx = (_Float16)(tx - (float)bx);
        _Float16 cy = (_Float16)(ty - (float)by);
        _Float16 cz = (_Float16)(tz - (float)bz);
        half8 h0 = {bx, by, bz, cx, cy, cz, bx, by};
        half8 h1 = {bz, ONE, ONE, Z, Z, Z, Z, Z};
        half8 bi = hk ? h1 : h0;
        if (i == 0) { bf0 = bi; aa0 = aa; }
        else if (i == 1) { bf1 = bi; aa1 = aa; }
        else if (i == 2) { bf2 = bi; aa2 = aa; }
        else { bf3 = bi; aa3 = aa; }
    }

    f32x16 zc;
#pragma unroll
    for (int i = 0; i < 16; ++i) zc[i] = 0.0f;

    float rm0 = __builtin_huge_valf(), rm1 = __builtin_huge_valf();
    float rm2 = __builtin_huge_valf(), rm3 = __builtin_huge_valf();

    // A-frag pointer: lane's 16B within the slice's first tile.
    const half8* __restrict__ ap =
        (const half8*)(Ap + (size_t)b * AHALF_B + (size_t)ns * TSLICE * 512) + lane;

    half8 af = ap[0];
#pragma unroll 4
    for (int t = 0; t < TSLICE; ++t) {
        half8 afn = ap[(t + 1) * 64];   // prefetch; overreads 1 KB at t=31 (ws padded)
        f32x16 c0 = __builtin_amdgcn_mfma_f32_32x32x16_f16(af, bf0, zc, 0, 0, 0);
        f32x16 c1 = __builtin_amdgcn_mfma_f32_32x32x16_f16(af, bf1, zc, 0, 0, 0);
        f32x16 c2 = __builtin_amdgcn_mfma_f32_32x32x16_f16(af, bf2, zc, 0, 0, 0);
        f32x16 c3 = __builtin_amdgcn_mfma_f32_32x32x16_f16(af, bf3, zc, 0, 0, 0);
        rm0 = min16acc(rm0, c0);
        rm1 = min16acc(rm1, c1);
        rm2 = min16acc(rm2, c2);
        rm3 = min16acc(rm3, c3);
        af = afn;
    }

    // complete the 32-row min (lanes l, l^32 cover complementary rows, same col)
    rm0 = fminf(rm0, __shfl_xor(rm0, 32, 64));
    rm1 = fminf(rm1, __shfl_xor(rm1, 32, 64));
    rm2 = fminf(rm2, __shfl_xor(rm2, 32, 64));
    rm3 = fminf(rm3, __shfl_xor(rm3, 32, 64));

    // plain coalesced partial stores part[ns][b][col] (no init required)
    float* p = part + ((size_t)ns * BATCH + b) * KPTS;
    if (hk == 0) {
        p[m0]      = fmaxf(rm0 + aa0, 0.0f);
        p[m0 + 32] = fmaxf(rm1 + aa1, 0.0f);
        p[m0 + 64] = fmaxf(rm2 + aa2, 0.0f);
        p[m0 + 96] = fmaxf(rm3 + aa3, 0.0f);
    }
}

// 8 blocks (one per batch), 1024 threads: min over slices, max over columns.
__global__ __launch_bounds__(1024) void reduceB(const float* __restrict__ part,
                                                const float* __restrict__ w,
                                                float* __restrict__ out) {
    const int b = blockIdx.x;
    const int tid = threadIdx.x;

    float mx = 0.0f;   // partials are clamped nonneg
#pragma unroll
    for (int h = 0; h < 2; ++h) {
        const int c4 = tid + h * 1024;       // float4 index, 2048 per row
        float4 v[NSPLIT];
#pragma unroll
        for (int s = 0; s < NSPLIT; ++s)
            v[s] = *(const float4*)(part + ((size_t)s * BATCH + b) * KPTS + (size_t)c4 * 4);
        float4 mn = v[0];
#pragma unroll
        for (int s = 1; s < NSPLIT; ++s) {
            mn.x = fminf(mn.x, v[s].x); mn.y = fminf(mn.y, v[s].y);
            mn.z = fminf(mn.z, v[s].z); mn.w = fminf(mn.w, v[s].w);
        }
        mx = fmaxf(mx, fmaxf(fmaxf(mn.x, mn.y), fmaxf(mn.z, mn.w)));
    }

#pragma unroll
    for (int off = 32; off; off >>= 1)
        mx = fmaxf(mx, __shfl_xor(mx, off, 64));

    __shared__ float red[16];
    if ((tid & 63) == 0) red[tid >> 6] = mx;
    __syncthreads();
    if (tid == 0) {
        float m2 = red[0];
#pragma unroll
        for (int i = 1; i < 16; ++i) m2 = fmaxf(m2, red[i]);
        atomicAdd(out, m2 * w[b] * (1.0f / BATCH));
    }
}

extern "C" void kernel_launch(void* const* d_in, const int* in_sizes, int n_in,
                              void* d_out, int out_size, void* d_ws, size_t ws_size,
                              hipStream_t stream) {
    const float* adv = (const float*)d_in[0];   // [B, K, 3]
    const float* ori = (const float*)d_in[1];   // [B, K, 3]
    const float* w   = (const float*)d_in[2];   // [B]
    float* out = (float*)d_out;

    char* ws = (char*)d_ws;
    _Float16* Ap = (_Float16*)ws;                                  // 2 MB A'
    // 4 KB pad after A' absorbs the benign 1-tile prefetch overread.
    float* part = (float*)(ws + (size_t)(2 << 20) + 4096);         // 2 MB partials

    prep<<<(BATCH * KPTS) / 256, 256, 0, stream>>>(ori, Ap);
    hausdorff<<<BATCH * MCHUNK * NSPLIT, 256, 0, stream>>>(adv, (const _Float16*)Ap, part, out);
    reduceB<<<BATCH, 1024, 0, stream>>>((const float*)part, w, out);
}

// Round 6
// 78.692 us; speedup vs baseline: 1.1332x; 1.1332x over previous
//
#include <hip/hip_runtime.h>

// Hausdorff adv2ori via MFMA: B=8, K=8192.
// dist(n,m) = oo_n + aa_m - 2*o.a ; C = mfma(A',B') = oo_n - 2*o.a (fp16 hi/lo split)
// loss = mean_b( w_b * max_m min_n dist )
//
// K=16 slot packing (one 32x32x16_f16 MFMA per 32x32 pair tile):
//   A'(ori n): [oh.x oh.y oh.z | oh.x oh.y oh.z | ol.x ol.y ol.z | oo_h oo_l | 0 x5]
//   B'(adv m): [bh.x bh.y bh.z | bl.x bl.y bl.z | bh.x bh.y bh.z | 1    1    | 0 x5]
//   b = -2*a; dropped ol.bl terms ~1e-6; fp32 accumulate. absmax=0 in R1-R5.
//
// R5 post-mortem: main kernel invariant at ~30-35us across 4 structural
// variants => bottleneck never was staging/conflicts/barriers. R1's counter row
// showed VGPR_Count=32 -> compiler put f32x16 accumulators in AGPRs; every MFMA
// pays 16 v_accvgpr_read (+ churn) to feed the min tree: ~4x the matrix time,
// identical in all variants. R6: inline-asm VGPR-form MFMA ("=&v" outputs, C=zc
// kept in VGPRs, D!=C so no re-zero; s_nop tail for the MFMA->VALU hazard the
// compiler can't see through asm). Single main kernel: slice staged once into
// 33KB tile-planar LDS (conflict-free), one barrier, 32 barrier-free tiles.

#define KPTS 8192
#define BATCH 8
#define NSPLIT 8                      // row slices (bid&7 -> per-XCD reuse)
#define RBLK (KPTS / NSPLIT)          // 1024 rows per slice
#define TSLICE (RBLK / 32)            // 32 MFMA row-tiles per slice
#define CBLK 512                      // adv columns per block (4 waves x 128)
#define MCHUNK (KPTS / CBLK)          // 16

typedef _Float16 half8 __attribute__((ext_vector_type(8)));
typedef float f32x16 __attribute__((ext_vector_type(16)));

// min over 16 accum values folded into running min rm (min3-fusable tree)
__device__ __forceinline__ float min16acc(float rm, const f32x16 c) {
    float u0 = fminf(fminf(c[0],  c[1]),  c[2]);
    float u1 = fminf(fminf(c[3],  c[4]),  c[5]);
    float u2 = fminf(fminf(c[6],  c[7]),  c[8]);
    float u3 = fminf(fminf(c[9],  c[10]), c[11]);
    float u4 = fminf(fminf(c[12], c[13]), c[14]);
    float u5 = fminf(fminf(u0, u1), c[15]);
    float u6 = fminf(fminf(u2, u3), u4);
    return fminf(fminf(u5, u6), rm);
}

__global__ __launch_bounds__(256) void hausdorff(const float* __restrict__ adv,
                                                 const float* __restrict__ ori,
                                                 float* __restrict__ part,
                                                 float* __restrict__ out) {
    // Tile-planar A' slice: tile t at halfs [t*512, t*512+512): lane reads
    // byte lane*16 within tile -> linear, conflict-free. +1 pad tile for the
    // harmless last-iteration prefetch.
    __shared__ _Float16 sA[(TSLICE + 1) * 512];   // 33 KB

    const int bid  = blockIdx.x;          // grid = 8 * 16 * 8 = 1024
    const int b    = bid >> 7;
    const int mc   = (bid >> 3) & (MCHUNK - 1);
    const int ns   = bid & 7;
    const int tid  = threadIdx.x;
    const int lane = tid & 63;
    const int wv   = tid >> 6;
    const int r    = lane & 31;           // MFMA row/col index
    const int hk   = lane >> 5;           // K-half

    if (bid == 0 && tid == 0) out[0] = 0.0f;   // for reduceB's atomicAdd

    const _Float16 Z = (_Float16)0.0f, ONE = (_Float16)1.0f;

    // ---- B-fragments + aa for this wave's 4 column groups ----
    const float* advb = adv + (size_t)b * KPTS * 3;
    const int m0 = mc * CBLK + wv * 128 + r;
    half8 bf0, bf1, bf2, bf3;
    float aa0, aa1, aa2, aa3;
#pragma unroll
    for (int i = 0; i < 4; ++i) {
        const int m = m0 + 32 * i;
        float ax = advb[3 * m], ay = advb[3 * m + 1], az = advb[3 * m + 2];
        float aa = ax * ax + ay * ay + az * az;
        float tx = -2.f * ax, ty = -2.f * ay, tz = -2.f * az;
        _Float16 bx = (_Float16)tx, by = (_Float16)ty, bz = (_Float16)tz;
        _Float16 cx = (_Float16)(tx - (float)bx);
        _Float16 cy = (_Float16)(ty - (float)by);
        _Float16 cz = (_Float16)(tz - (float)bz);
        half8 h0 = {bx, by, bz, cx, cy, cz, bx, by};
        half8 h1 = {bz, ONE, ONE, Z, Z, Z, Z, Z};
        half8 bi = hk ? h1 : h0;
        if (i == 0) { bf0 = bi; aa0 = aa; }
        else if (i == 1) { bf1 = bi; aa1 = aa; }
        else if (i == 2) { bf2 = bi; aa2 = aa; }
        else { bf3 = bi; aa3 = aa; }
    }

    // ---- stage + convert this block's 1024-row slice into LDS (once) ----
    const float* orib = ori + ((size_t)b * KPTS + (size_t)ns * RBLK) * 3;
#pragma unroll
    for (int i = 0; i < 4; ++i) {
        const int rr = tid + i * 256;
        const float* op = orib + (size_t)rr * 3;
        float x = op[0], y = op[1], z = op[2];
        float oo = x * x + y * y + z * z;
        _Float16 hx = (_Float16)x, hy = (_Float16)y, hz = (_Float16)z;
        _Float16 lx = (_Float16)(x - (float)hx);
        _Float16 ly = (_Float16)(y - (float)hy);
        _Float16 lz = (_Float16)(z - (float)hz);
        _Float16 oh = (_Float16)oo;
        _Float16 ol = (_Float16)(oo - (float)oh);
        half8 a0 = {hx, hy, hz, hx, hy, hz, lx, ly};
        half8 a1 = {lz, oh, ol, Z, Z, Z, Z, Z};
        const int off = ((rr >> 5) << 9) + ((rr & 31) << 3);
        *(half8*)(&sA[off])       = a0;
        *(half8*)(&sA[off + 256]) = a1;
    }
    __syncthreads();   // the only barrier

    f32x16 zc;
#pragma unroll
    for (int i = 0; i < 16; ++i) zc[i] = 0.0f;

    float rm0 = __builtin_huge_valf(), rm1 = __builtin_huge_valf();
    float rm2 = __builtin_huge_valf(), rm3 = __builtin_huge_valf();

    const _Float16* apl = sA + lane * 8;   // lane's 16B within tile 0
    half8 af = *(const half8*)apl;

    for (int t = 0; t < TSLICE; ++t) {
        half8 afn = *(const half8*)(apl + (size_t)(t + 1) * 512);  // prefetch (pad tile at t=31)

        // VGPR-form MFMA: results in VGPRs ("=&v"), C-in zc stays zero (D!=C,
        // no re-zero, no accvgpr churn). s_nop tail covers MFMA->VALU hazard.
        f32x16 d0, d1, d2, d3;
        asm("v_mfma_f32_32x32x16_f16 %0, %4, %5, %9\n\t"
            "v_mfma_f32_32x32x16_f16 %1, %4, %6, %9\n\t"
            "v_mfma_f32_32x32x16_f16 %2, %4, %7, %9\n\t"
            "v_mfma_f32_32x32x16_f16 %3, %4, %8, %9\n\t"
            "s_nop 7\n\ts_nop 7\n\ts_nop 7\n\ts_nop 7"
            : "=&v"(d0), "=&v"(d1), "=&v"(d2), "=&v"(d3)
            : "v"(af), "v"(bf0), "v"(bf1), "v"(bf2), "v"(bf3), "v"(zc));

        rm0 = min16acc(rm0, d0);
        rm1 = min16acc(rm1, d1);
        rm2 = min16acc(rm2, d2);
        rm3 = min16acc(rm3, d3);
        af = afn;
    }

    // complete the 32-row min (lanes l, l^32 cover complementary rows, same col)
    rm0 = fminf(rm0, __shfl_xor(rm0, 32, 64));
    rm1 = fminf(rm1, __shfl_xor(rm1, 32, 64));
    rm2 = fminf(rm2, __shfl_xor(rm2, 32, 64));
    rm3 = fminf(rm3, __shfl_xor(rm3, 32, 64));

    // plain coalesced partial stores part[ns][b][col] (no init required)
    float* p = part + ((size_t)ns * BATCH + b) * KPTS;
    if (hk == 0) {
        p[m0]      = fmaxf(rm0 + aa0, 0.0f);
        p[m0 + 32] = fmaxf(rm1 + aa1, 0.0f);
        p[m0 + 64] = fmaxf(rm2 + aa2, 0.0f);
        p[m0 + 96] = fmaxf(rm3 + aa3, 0.0f);
    }
}

// 8 blocks (one per batch), 1024 threads: min over slices, max over columns.
__global__ __launch_bounds__(1024) void reduceB(const float* __restrict__ part,
                                                const float* __restrict__ w,
                                                float* __restrict__ out) {
    const int b = blockIdx.x;
    const int tid = threadIdx.x;

    float mx = 0.0f;   // partials are clamped nonneg
#pragma unroll
    for (int h = 0; h < 2; ++h) {
        const int c4 = tid + h * 1024;       // float4 index, 2048 per row
        float4 v[NSPLIT];
#pragma unroll
        for (int s = 0; s < NSPLIT; ++s)
            v[s] = *(const float4*)(part + ((size_t)s * BATCH + b) * KPTS + (size_t)c4 * 4);
        float4 mn = v[0];
#pragma unroll
        for (int s = 1; s < NSPLIT; ++s) {
            mn.x = fminf(mn.x, v[s].x); mn.y = fminf(mn.y, v[s].y);
            mn.z = fminf(mn.z, v[s].z); mn.w = fminf(mn.w, v[s].w);
        }
        mx = fmaxf(mx, fmaxf(fmaxf(mn.x, mn.y), fmaxf(mn.z, mn.w)));
    }

#pragma unroll
    for (int off = 32; off; off >>= 1)
        mx = fmaxf(mx, __shfl_xor(mx, off, 64));

    __shared__ float red[16];
    if ((tid & 63) == 0) red[tid >> 6] = mx;
    __syncthreads();
    if (tid == 0) {
        float m2 = red[0];
#pragma unroll
        for (int i = 1; i < 16; ++i) m2 = fmaxf(m2, red[i]);
        atomicAdd(out, m2 * w[b] * (1.0f / BATCH));
    }
}

extern "C" void kernel_launch(void* const* d_in, const int* in_sizes, int n_in,
                              void* d_out, int out_size, void* d_ws, size_t ws_size,
                              hipStream_t stream) {
    const float* adv = (const float*)d_in[0];   // [B, K, 3]
    const float* ori = (const float*)d_in[1];   // [B, K, 3]
    const float* w   = (const float*)d_in[2];   // [B]
    float* out = (float*)d_out;
    float* part = (float*)d_ws;                 // NSPLIT*B*K floats = 2 MB

    hausdorff<<<BATCH * MCHUNK * NSPLIT, 256, 0, stream>>>(adv, ori, part, out);
    reduceB<<<BATCH, 1024, 0, stream>>>((const float*)part, w, out);
}